// Round 6
// baseline (465.881 us; speedup 1.0000x reference)
//
#include <hip/hip_runtime.h>
#include <cstdint>
#include <cstddef>

#define NN    8192
#define DIN   256
#define DOUT  128
#define LRA   0.2f

// ---------------------------------------------------------------------------
// K1: h = input@W  +  s,t computed straight from the accumulator registers.
// 512 blocks x 256 threads; 16 rows/block. (Verified passing in R3/R4.)
// ---------------------------------------------------------------------------
__global__ __launch_bounds__(256) void gemm_st_kernel(
    const float* __restrict__ input, const float* __restrict__ W,
    const float* __restrict__ a_self, const float* __restrict__ a_neighs,
    float* __restrict__ h, float* __restrict__ s_arr,
    float* __restrict__ t_arr)
{
    __shared__ float tile[16][DIN];   // 16 KB
    __shared__ float pr[4][16];       // per-wave {s,t} partials for 8 rows
    const int tid  = threadIdx.x;
    const int row0 = blockIdx.x * 16;
    {
        const float4* in4 = (const float4*)(input + (size_t)row0 * DIN);
        float4* t4 = (float4*)&tile[0][0];
        #pragma unroll
        for (int k = 0; k < 4; ++k) t4[tid + k * 256] = in4[tid + k * 256];
    }
    __syncthreads();
    const int c    = tid & 127;
    const int g    = tid >> 7;        // 0..1
    const int lane = tid & 63;
    const int wave = tid >> 6;        // 0..3
    float acc[8];
    #pragma unroll
    for (int m = 0; m < 8; ++m) acc[m] = 0.f;
    for (int k = 0; k < DIN; k += 4) {
        const float w0 = W[(k + 0) * DOUT + c];
        const float w1 = W[(k + 1) * DOUT + c];
        const float w2 = W[(k + 2) * DOUT + c];
        const float w3 = W[(k + 3) * DOUT + c];
        #pragma unroll
        for (int m = 0; m < 8; ++m) {
            const float4 av = *(const float4*)&tile[g * 8 + m][k];
            acc[m] += av.x * w0 + av.y * w1 + av.z * w2 + av.w * w3;
        }
    }
    #pragma unroll
    for (int m = 0; m < 8; ++m)
        h[(size_t)(row0 + g * 8 + m) * DOUT + c] = acc[m];

    const float as = a_self[c];
    const float an = a_neighs[c];
    #pragma unroll
    for (int m = 0; m < 8; ++m) {
        float vs = acc[m] * as;
        float vt = acc[m] * an;
        for (int off = 32; off > 0; off >>= 1) {
            vs += __shfl_down(vs, off);
            vt += __shfl_down(vt, off);
        }
        if (lane == 0) { pr[wave][2 * m] = vs; pr[wave][2 * m + 1] = vt; }
    }
    __syncthreads();
    if (tid < 16) {
        const int m  = tid & 7;
        const int gg = tid >> 3;
        const int r  = row0 + gg * 8 + m;
        s_arr[r] = pr[2 * gg][2 * m]     + pr[2 * gg + 1][2 * m];
        t_arr[r] = pr[2 * gg][2 * m + 1] + pr[2 * gg + 1][2 * m + 1];
    }
}

// ---------------------------------------------------------------------------
// K2: descending rank of t by counting; order[rank]=j, tsorted[rank]=t[j].
// (Verified passing in R3/R4.)
// ---------------------------------------------------------------------------
__global__ __launch_bounds__(256) void rank_kernel(
    const float* __restrict__ t, int* __restrict__ order,
    float* __restrict__ tsorted)
{
    __shared__ float tl[NN];        // 32 KB
    __shared__ int   part[8][32];
    for (int k = threadIdx.x; k < NN; k += 256) tl[k] = t[k];
    __syncthreads();
    const int jloc = threadIdx.x & 31;
    const int seg  = threadIdx.x >> 5;
    const int j    = blockIdx.x * 32 + jloc;
    const float tj = tl[j];
    int r = 0;
    const int k0 = seg * (NN / 8);
    for (int i = 0; i < NN / 8; ++i) {
        const int k = k0 + ((i + seg * 4) & (NN / 8 - 1));  // bank-rotated
        const float tk = tl[k];
        r += (tk > tj || (tk == tj && k < j)) ? 1 : 0;
    }
    part[seg][jloc] = r;
    __syncthreads();
    if (threadIdx.x < 32) {
        int rr = 0;
        #pragma unroll
        for (int ss = 0; ss < 8; ++ss) rr += part[ss][threadIdx.x];
        const int jj = blockIdx.x * 32 + threadIdx.x;
        order[rr]   = jj;
        tsorted[rr] = tl[jj];
    }
}

// ---------------------------------------------------------------------------
// K3: one block per row. Pure sync-free stream: softmax denominator over the
// adj row (int4) + t (L2-hot float4), AND the row's 8192-bit validity mask
// written to global (layout: word = ((j>>8)<<2)|(j&3), bit = (j&255)>>2).
// ---------------------------------------------------------------------------
__global__ __launch_bounds__(256) void denom_kernel(
    const int* __restrict__ adj, const float* __restrict__ s_arr,
    const float* __restrict__ t_arr, const float* __restrict__ tsorted,
    float* __restrict__ denom, unsigned long long* __restrict__ mask)
{
    __shared__ float red[4];
    const int row  = blockIdx.x;
    const int tid  = threadIdx.x;
    const int lane = tid & 63;
    const int wave = tid >> 6;

    const float s    = s_arr[row];
    const float tmax = tsorted[0];
    const float zc   = s + tmax;
    const float C    = fmaxf(zc, LRA * zc);   // lrelu(s+tmax) >= every e

    const int4*   arow = (const int4*)(adj + (size_t)row * NN);
    const float4* t4   = (const float4*)t_arr;
    unsigned long long* mrow = mask + (size_t)row * 128;

    float acc = 0.f;
    #pragma unroll
    for (int k = 0; k < 8; ++k) {
        const int idx = tid + (k << 8);
        const int4   a  = arow[idx];
        const float4 tv = t4[idx];
        const int vx = a.x > 0, vy = a.y > 0, vz = a.z > 0, vw = a.w > 0;
        float z, e;
        z = s + tv.x; e = fmaxf(z, LRA * z); if (vx) acc += __expf(e - C);
        z = s + tv.y; e = fmaxf(z, LRA * z); if (vy) acc += __expf(e - C);
        z = s + tv.z; e = fmaxf(z, LRA * z); if (vz) acc += __expf(e - C);
        z = s + tv.w; e = fmaxf(z, LRA * z); if (vw) acc += __expf(e - C);
        const unsigned long long b0 = __ballot(vx);
        const unsigned long long b1 = __ballot(vy);
        const unsigned long long b2 = __ballot(vz);
        const unsigned long long b3 = __ballot(vw);
        if (lane < 4) {   // 4-lane coalesced 32B store: words (4k+wave)*4+c
            const unsigned long long bv =
                (lane == 0) ? b0 : (lane == 1) ? b1 : (lane == 2) ? b2 : b3;
            mrow[(4 * k + wave) * 4 + lane] = bv;
        }
    }
    for (int off = 32; off > 0; off >>= 1) acc += __shfl_down(acc, off);
    if (lane == 0) red[wave] = acc;
    __syncthreads();
    if (tid == 0) denom[row] = red[0] + red[1] + red[2] + red[3];
}

// ---------------------------------------------------------------------------
// K4: ONE WAVE PER ROW (8192 waves chip-wide, zero LDS, zero block syncs).
// Mask row register-resident (16 B/lane); sorted-t walk finds the
// top-(action+1) threshold via ballots; gather broadcasts (j,w) via shfl and
// loads h rows coalesced (float2/lane); each lane owns 2 output columns.
// ---------------------------------------------------------------------------
__global__ __launch_bounds__(256) void walk_kernel(
    const float* __restrict__ s_arr, const int* __restrict__ order,
    const float* __restrict__ tsorted,
    const unsigned long long* __restrict__ mask,
    const float* __restrict__ denom, const int* __restrict__ action,
    const float* __restrict__ h, const int* __restrict__ policy,
    float* __restrict__ out)
{
    const int row  = (blockIdx.x * 256 + threadIdx.x) >> 6;
    const int lane = threadIdx.x & 63;

    const float s    = s_arr[row];
    const float tmax = tsorted[0];
    const float zc   = s + tmax;
    const float C    = fmaxf(zc, LRA * zc);

    // lane holds mask words {2*lane, 2*lane+1} (128 words/row)
    const ulonglong2 mw =
        *(const ulonglong2*)(mask + (size_t)row * 128 + 2 * lane);

    int K = policy[0] ? (action[row] + 1) : 0x7FFFFFFF;

    float2 acc = make_float2(0.f, 0.f);
    float tthr = -3.0e38f;
    int found = 0, cnt = 0, base = 0;

    while (true) {
        const int p    = base + lane;
        const int j    = order[p];
        const float tjv = tsorted[p];
        const int W    = ((j >> 8) << 2) | (j & 3);
        const int bit  = (j & 255) >> 2;
        const unsigned long long wa = __shfl(mw.x, W >> 1);
        const unsigned long long wb = __shfl(mw.y, W >> 1);
        const unsigned long long word = (W & 1) ? wb : wa;
        const int valid = (int)((word >> bit) & 1ull);

        const unsigned long long vm = __ballot(valid);
        if (!found) {
            const int cv = __popcll(vm);
            if (cnt + cv >= K) {
                const int need   = K - cnt;
                const int myrank = __popcll(vm & ((1ull << lane) - 1ull)) + 1;
                const unsigned long long pm =
                    __ballot(valid && (myrank == need));
                const int L = __ffsll((long long)pm) - 1;
                tthr  = __shfl(tjv, L);
                found = 1;
            } else {
                cnt += cv;
            }
        }
        const int selected = valid && (tjv >= tthr);
        float wv = 0.f;
        if (selected) {
            const float z = s + tjv;
            const float e = fmaxf(z, LRA * z);
            wv = __expf(e - C);
        }
        unsigned long long sm = __ballot(selected);
        while (sm) {   // ~K selected total across the whole walk
            const int L = __ffsll((long long)sm) - 1;
            sm &= sm - 1ull;
            const int   jj = __shfl(j, L);
            const float w  = __shfl(wv, L);
            const float2 hv =
                *(const float2*)&h[(size_t)jj * DOUT + 2 * lane];
            acc.x += w * hv.x;
            acc.y += w * hv.y;
        }
        base += 64;
        if (base >= NN) break;
        if (found && tsorted[base] < tthr) break;
    }

    const float linv = 1.f / denom[row];
    float vx = acc.x * linv, vy = acc.y * linv;
    vx = (vx > 0.f) ? vx : expm1f(vx);
    vy = (vy > 0.f) ? vy : expm1f(vy);
    *(float2*)&out[(size_t)row * DOUT + 2 * lane] = make_float2(vx, vy);
}

// ---------------------------------------------------------------------------
extern "C" void kernel_launch(void* const* d_in, const int* in_sizes, int n_in,
                              void* d_out, int out_size, void* d_ws,
                              size_t ws_size, hipStream_t stream)
{
    const float* input    = (const float*)d_in[0];
    const int*   adj      = (const int*)d_in[1];
    const int*   action   = (const int*)d_in[2];
    const float* W        = (const float*)d_in[3];
    const float* a_self   = (const float*)d_in[4];
    const float* a_neighs = (const float*)d_in[5];
    const int*   policy   = (const int*)d_in[6];
    float* out = (float*)d_out;

    float* ws      = (float*)d_ws;
    float* h       = ws;                        // 8192*128 fp32 = 4 MB
    float* s       = ws + (size_t)NN * DOUT;    // 8192 fp32
    float* t       = s + NN;                    // 8192 fp32
    float* tsorted = t + NN;                    // 8192 fp32
    float* denom   = tsorted + NN;              // 8192 fp32
    int*   order   = (int*)(denom + NN);        // 8192 int32
    unsigned long long* mask =
        (unsigned long long*)(order + NN);      // 8192*128 u64 = 8 MB

    hipLaunchKernelGGL(gemm_st_kernel, dim3(512), dim3(256), 0, stream,
                       input, W, a_self, a_neighs, h, s, t);
    hipLaunchKernelGGL(rank_kernel, dim3(256), dim3(256), 0, stream,
                       t, order, tsorted);
    hipLaunchKernelGGL(denom_kernel, dim3(NN), dim3(256), 0, stream,
                       adj, s, t, tsorted, denom, mask);
    hipLaunchKernelGGL(walk_kernel, dim3(NN / 4), dim3(256), 0, stream,
                       s, order, tsorted, mask, denom, action, h, policy, out);
}